// Round 14
// baseline (443.963 us; speedup 1.0000x reference)
//
#include <hip/hip_runtime.h>
#include <math.h>

#define BB 2
#define SS 2048
#define EE 1024
#define HH 16
#define DD 64
#define YAT_EPS 1e-5f

typedef __attribute__((ext_vector_type(8))) short bf16x8;
typedef __attribute__((ext_vector_type(4))) short short4v;
typedef __attribute__((ext_vector_type(4))) float f32x4;
#define MFMA16(a, b, c) __builtin_amdgcn_mfma_f32_16x16x32_bf16((a), (b), (c), 0, 0, 0)

#if __has_builtin(__builtin_amdgcn_exp2f)
#define EXP2(x) __builtin_amdgcn_exp2f(x)
#else
#define EXP2(x) exp2f(x)
#endif
#if __has_builtin(__builtin_amdgcn_rcpf)
#define RCPF(x) __builtin_amdgcn_rcpf(x)
#else
#define RCPF(x) (1.0f / (x))
#endif

__device__ __forceinline__ unsigned short f2bf(float x) {
    unsigned int u = __float_as_uint(x);
    u += 0x7FFFu + ((u >> 16) & 1u);   // RNE
    return (unsigned short)(u >> 16);
}
__device__ __forceinline__ float bf2f(unsigned short h) {
    return __uint_as_float(((unsigned int)h) << 16);
}
// truncating fp32->bf16 (1 op; P in [0,1], bias ~0.1% — renorm-safe)
__device__ __forceinline__ short f2bf_t(float x) {
    return (short)(__float_as_uint(x) >> 16);
}

__device__ __forceinline__ void async_ld16(void* lds, const void* g) {
    __builtin_amdgcn_global_load_lds(
        (const __attribute__((address_space(1))) unsigned int*)g,
        (__attribute__((address_space(3))) unsigned int*)lds, 16, 0, 0);
}

// fp32 -> bf16 hi/lo split (grid covers n/4 float4s exactly)
__global__ __launch_bounds__(256) void split_f32(const float* __restrict__ in,
                                                 unsigned short* __restrict__ hi,
                                                 unsigned short* __restrict__ lo,
                                                 int n4) {
    int i = blockIdx.x * 256 + threadIdx.x;
    if (i >= n4) return;
    float4 v = ((const float4*)in)[i];
    ushort4 h, l;
    h.x = f2bf(v.x); l.x = f2bf(v.x - bf2f(h.x));
    h.y = f2bf(v.y); l.y = f2bf(v.y - bf2f(h.y));
    h.z = f2bf(v.z); l.z = f2bf(v.z - bf2f(h.z));
    h.w = f2bf(v.w); l.w = f2bf(v.w - bf2f(h.w));
    ((ushort4*)hi)[i] = h;
    ((ushort4*)lo)[i] = l;
}

// fused hi/lo split of the four weight matrices; lo only needed for Wq,Wk
__global__ __launch_bounds__(256) void split_w4(
        const float* __restrict__ Wq, const float* __restrict__ Wk,
        const float* __restrict__ Wv, const float* __restrict__ Wo,
        unsigned short* __restrict__ Whi, unsigned short* __restrict__ Wlo,
        unsigned short* __restrict__ Wohi) {
    int i = blockIdx.x * 256 + threadIdx.x;      // < EE*EE/4
    int y = blockIdx.y;
    const float* src = y == 0 ? Wq : y == 1 ? Wk : y == 2 ? Wv : Wo;
    unsigned short* hi = y < 3 ? Whi + (size_t)y * EE * EE : Wohi;
    float4 v = ((const float4*)src)[i];
    ushort4 h;
    h.x = f2bf(v.x); h.y = f2bf(v.y); h.z = f2bf(v.z); h.w = f2bf(v.w);
    ((ushort4*)hi)[i] = h;
    if (y < 2) {
        unsigned short* lo = Wlo + (size_t)y * EE * EE;
        ushort4 l;
        l.x = f2bf(v.x - bf2f(h.x));
        l.y = f2bf(v.y - bf2f(h.y));
        l.z = f2bf(v.z - bf2f(h.z));
        l.w = f2bf(v.w - bf2f(h.w));
        ((ushort4*)lo)[i] = l;
    }
}

// bf16 MFMA GEMM, PASSES=3 (hi/lo Markidis) or 1 (plain bf16).
// C[M,N] = A[M,K] @ B[N,K]^T + bias.
// MODE 0: fp32 out + bias(bq).
// MODE 1: q/k epilogue (N=2048): bf16 hi(+lo for q) [B,H,S,D] + fp32 norms.
// MODE 2: v epilogue (N=1024): bf16 [B,H,S,D], bias in bv.
template <int MODE, int PASSES>
__global__ __launch_bounds__(256, 2) void gemm3p(
        const unsigned short* __restrict__ Ahi, const unsigned short* __restrict__ Alo,
        const unsigned short* __restrict__ Bhi, const unsigned short* __restrict__ Blo,
        const float* __restrict__ bq, const float* __restrict__ bk,
        const float* __restrict__ bv,
        float* __restrict__ Cf,
        unsigned short* __restrict__ qhi, unsigned short* __restrict__ qlo,
        unsigned short* __restrict__ khi,
        unsigned short* __restrict__ v_sd,
        float* __restrict__ sqn, float* __restrict__ skn,
        int M, int N, int K) {
    __shared__ __align__(16) unsigned short LA_hi[128 * 32];
    __shared__ __align__(16) unsigned short LA_lo[128 * 32];
    __shared__ __align__(16) unsigned short LB_hi[128 * 32];
    __shared__ __align__(16) unsigned short LB_lo[128 * 32];

    const int t = threadIdx.x;
    const int w = t >> 6, lane = t & 63;
    const int quad = lane >> 4, lr = lane & 15;
    const int wy = w & 1, wx = w >> 1;
    const int m0 = blockIdx.y * 128, n0 = blockIdx.x * 128;

    const unsigned short* gsrc = nullptr;
    unsigned short* ldst = nullptr;
    if (w == 0)      { gsrc = Ahi + (size_t)m0 * K; ldst = LA_hi; }
    else if (w == 2) { gsrc = Bhi + (size_t)n0 * K; ldst = LB_hi; }
    else if (PASSES == 3 && w == 1) { gsrc = Alo + (size_t)m0 * K; ldst = LA_lo; }
    else if (PASSES == 3 && w == 3) { gsrc = Blo + (size_t)n0 * K; ldst = LB_lo; }
    const unsigned short* gl = gsrc ? gsrc + (size_t)(lane >> 2) * K + (lane & 3) * 8
                                    : nullptr;

    f32x4 acc[4][4];
    #pragma unroll
    for (int i = 0; i < 4; ++i)
        #pragma unroll
        for (int j = 0; j < 4; ++j)
            acc[i][j] = (f32x4){0.f, 0.f, 0.f, 0.f};

    for (int k0 = 0; k0 < K; k0 += 32) {
        __syncthreads();
        if (gl) {
            #pragma unroll
            for (int i = 0; i < 8; ++i)
                async_ld16(ldst + i * 512, gl + (size_t)i * 16 * K + k0);
        }
        __syncthreads();
        bf16x8 ah[4], al[4], bh_[4], bl_[4];
        #pragma unroll
        for (int i = 0; i < 4; ++i) {
            ah[i]  = *(const bf16x8*)&LA_hi[(wy * 64 + i * 16 + lr) * 32 + quad * 8];
            bh_[i] = *(const bf16x8*)&LB_hi[(wx * 64 + i * 16 + lr) * 32 + quad * 8];
            if (PASSES == 3) {
                al[i]  = *(const bf16x8*)&LA_lo[(wy * 64 + i * 16 + lr) * 32 + quad * 8];
                bl_[i] = *(const bf16x8*)&LB_lo[(wx * 64 + i * 16 + lr) * 32 + quad * 8];
            }
        }
        #pragma unroll
        for (int mg = 0; mg < 4; ++mg)
            #pragma unroll
            for (int ns = 0; ns < 4; ++ns) {
                f32x4 a = acc[mg][ns];
                a = MFMA16(ah[mg], bh_[ns], a);
                if (PASSES == 3) {
                    a = MFMA16(ah[mg], bl_[ns], a);
                    a = MFMA16(al[mg], bh_[ns], a);
                }
                acc[mg][ns] = a;
            }
    }

    const int ng = n0 + wx * 64;
    if (MODE == 0) {
        float bias_v[4];
        #pragma unroll
        for (int ns = 0; ns < 4; ++ns) bias_v[ns] = bq[ng + ns * 16 + lr];
        #pragma unroll
        for (int mg = 0; mg < 4; ++mg)
            #pragma unroll
            for (int r = 0; r < 4; ++r) {
                int m = m0 + wy * 64 + mg * 16 + quad * 4 + r;
                #pragma unroll
                for (int ns = 0; ns < 4; ++ns)
                    Cf[(size_t)m * N + ng + ns * 16 + lr] = acc[mg][ns][r] + bias_v[ns];
            }
    } else {
        const int path = MODE == 1 ? (ng >> 10) : 2;   // 0=q 1=k 2=v
        const int c = MODE == 1 ? (ng & 1023) : ng;
        const int h = c >> 6;
        const float* bias = path == 0 ? bq : path == 1 ? bk : bv;
        unsigned short* hi_p = path == 0 ? qhi : path == 1 ? khi : v_sd;
        float* nrm = path == 0 ? sqn : skn;
        float bias_v[4];
        #pragma unroll
        for (int ns = 0; ns < 4; ++ns) bias_v[ns] = bias[c + ns * 16 + lr];
        #pragma unroll
        for (int mg = 0; mg < 4; ++mg)
            #pragma unroll
            for (int r = 0; r < 4; ++r) {
                int m = m0 + wy * 64 + mg * 16 + quad * 4 + r;
                int b = m >> 11, s = m & (SS - 1);
                size_t base = ((size_t)(b * HH + h) * SS + s) * DD;
                float v4[4];
                #pragma unroll
                for (int ns = 0; ns < 4; ++ns) v4[ns] = acc[mg][ns][r] + bias_v[ns];
                if (path < 2) {
                    float pn = v4[0] * v4[0] + v4[1] * v4[1] + v4[2] * v4[2] + v4[3] * v4[3];
                    #pragma unroll
                    for (int off = 1; off < 16; off <<= 1) pn += __shfl_xor(pn, off);
                    if (lr == 0) nrm[(size_t)(b * HH + h) * SS + s] = pn;
                    #pragma unroll
                    for (int ns = 0; ns < 4; ++ns) {
                        unsigned short hv = f2bf(v4[ns]);
                        hi_p[base + ns * 16 + lr] = hv;
                        if (path == 0)
                            qlo[base + ns * 16 + lr] = f2bf(v4[ns] - bf2f(hv));
                    }
                } else {
                    #pragma unroll
                    for (int ns = 0; ns < 4; ++ns)
                        hi_p[base + ns * 16 + lr] = f2bf(v4[ns]);
                }
            }
    }
}

// [bh][s][d] -> [bh][d][s] bf16 transpose, 64x64 LDS tiles
__global__ __launch_bounds__(256) void transpose_v(const unsigned short* __restrict__ v_sd,
                                                   unsigned short* __restrict__ vt) {
    __shared__ unsigned short T[64][65];
    const int t = threadIdx.x;
    const int bh = blockIdx.y, s0 = blockIdx.x * 64;
    {
        int sl = t >> 2, d4 = (t & 3) * 16;
        const unsigned short* src = &v_sd[((size_t)bh * SS + s0 + sl) * DD + d4];
        bf16x8 a = *(const bf16x8*)src;
        bf16x8 b = *(const bf16x8*)(src + 8);
        #pragma unroll
        for (int j = 0; j < 8; ++j) {
            T[sl][d4 + j] = (unsigned short)a[j];
            T[sl][d4 + 8 + j] = (unsigned short)b[j];
        }
    }
    __syncthreads();
    {
        int dl = t >> 2, s4 = (t & 3) * 16;
        bf16x8 a, b;
        #pragma unroll
        for (int j = 0; j < 8; ++j) {
            a[j] = (short)T[s4 + j][dl];
            b[j] = (short)T[s4 + 8 + j][dl];
        }
        unsigned short* dst = &vt[((size_t)bh * DD + dl) * SS + s0 + s4];
        *(bf16x8*)dst = a;
        *(bf16x8*)(dst + 8) = b;
    }
}

// MFMA flash attention v8: WAVE-AUTONOMOUS, zero barriers. r13's regression
// was the 1024-block grid at 3 blocks/CU residency (2-round tail, occ 23.7%)
// plus all-wave coupling at the per-tile __syncthreads+vmcnt(0) drain. Now
// each wave owns 16 q-rows and iterates all 32 k-tiles itself: K fragments
// straight from global (r8-proven addressing; L2 serves re-reads), P in a
// private single-buffered per-wave LDS slice (same-wave dependence ordering),
// NO __syncthreads anywhere. LDS 8.7KB; natural VGPR need ~116 so
// launch_bounds(256,4) fits 128 -> 4 blocks/CU, grid 1024 = exactly one
// dispatch round, zero tail, waves free-run to hide chain latency.
__global__ __launch_bounds__(256, 4) void yat_attn_mfma(
        const unsigned short* __restrict__ qhi, const unsigned short* __restrict__ qlo,
        const unsigned short* __restrict__ khi,
        const unsigned short* __restrict__ vt,
        const float* __restrict__ sqn, const float* __restrict__ skn,
        const float* __restrict__ alphap,
        unsigned short* __restrict__ ctxhi) {
    __shared__ __align__(16) unsigned short Ps[4][16 * 68];   // per-wave slice

    const int t = threadIdx.x;
    const int w = t >> 6, lane = t & 63;
    const int quad = lane >> 4, lr = lane & 15;
    const int qt = blockIdx.x, bh = blockIdx.y;
    const int b = bh >> 4, h = bh & 15;
    const int row0 = qt * 64 + w * 16;
    // softmax in exp2 domain; max tracked in u = qk^2/d domain (monotone),
    // cscale*log2e applied only inside the exp argument (fma)
    const float cscale = powf(sqrtf((float)DD) / log1pf((float)DD), alphap[0])
                         * 1.4426950408889634f;

    // persistent Q fragments (B-operand: lane holds q-col = lr)
    bf16x8 qh[2], ql[2];
    #pragma unroll
    for (int kd = 0; kd < 2; ++kd) {
        size_t o = ((size_t)bh * SS + row0 + lr) * DD + kd * 32 + quad * 8;
        qh[kd] = *(const bf16x8*)&qhi[o];
        ql[kd] = *(const bf16x8*)&qlo[o];
    }
    const float sqe = sqn[(size_t)bh * SS + row0 + lr] + YAT_EPS;

    float m_r = -INFINITY, l_r = 0.f;   // m_r in u-domain
    f32x4 O[4];
    #pragma unroll
    for (int nd = 0; nd < 4; ++nd) O[nd] = (f32x4){0.f, 0.f, 0.f, 0.f};

    unsigned short* myP = Ps[w];
    const size_t kfrag_base = (size_t)bh * SS * DD + (size_t)lr * DD + quad * 8;
    const size_t skn_base = (size_t)bh * SS + quad * 4;

    for (int it = 0; it < SS / 64; ++it) {
        const int kbase = it * 64;
        // ---- QK'^T = K.(qh+ql)^T, K frags direct from global (L2-served) ----
        f32x4 acc[4];
        f32x4 sk4[4];
        #pragma unroll
        for (int st = 0; st < 4; ++st) {
            size_t o = kfrag_base + (size_t)(kbase + st * 16) * DD;
            bf16x8 kh0 = *(const bf16x8*)&khi[o];
            bf16x8 kh1 = *(const bf16x8*)&khi[o + 32];
            sk4[st] = *(const f32x4*)&skn[skn_base + kbase + st * 16];
            f32x4 a = (f32x4){0.f, 0.f, 0.f, 0.f};
            a = MFMA16(kh0, qh[0], a);
            a = MFMA16(kh1, qh[1], a);
            a = MFMA16(kh0, ql[0], a);
            a = MFMA16(kh1, ql[1], a);
            acc[st] = a;
        }
        // ---- V fragments (issue early; latency covered by softmax) ----
        bf16x8 vf[4][2];
        #pragma unroll
        for (int nd = 0; nd < 4; ++nd)
            #pragma unroll
            for (int kk = 0; kk < 2; ++kk)
                vf[nd][kk] = *(const bf16x8*)&vt[((size_t)bh * DD + nd * 16 + lr) * SS
                                                 + kbase + kk * 32 + quad * 8];
        // ---- softmax: u = qk^2/d in place, max in u-domain ----
        float mx = -INFINITY;
        #pragma unroll
        for (int st = 0; st < 4; ++st)
            #pragma unroll
            for (int r = 0; r < 4; ++r) {
                float qk = acc[st][r];
                float d = sqe + sk4[st][r] - 2.f * qk;
                float u = qk * qk * RCPF(d);
                acc[st][r] = u;
                mx = fmaxf(mx, u);
            }
        mx = fmaxf(mx, __shfl_xor(mx, 16));
        mx = fmaxf(mx, __shfl_xor(mx, 32));
        float mnew = fmaxf(m_r, mx);
        float cm = cscale * mnew;
        float aa = EXP2(__builtin_fmaf(cscale, m_r, -cm));
        m_r = mnew;
        float rs = 0.f;
        #pragma unroll
        for (int st = 0; st < 4; ++st) {
            float e0 = EXP2(__builtin_fmaf(cscale, acc[st][0], -cm));
            float e1 = EXP2(__builtin_fmaf(cscale, acc[st][1], -cm));
            float e2 = EXP2(__builtin_fmaf(cscale, acc[st][2], -cm));
            float e3 = EXP2(__builtin_fmaf(cscale, acc[st][3], -cm));
            rs += (e0 + e1) + (e2 + e3);
            short4v pv;
            pv[0] = f2bf_t(e0); pv[1] = f2bf_t(e1);
            pv[2] = f2bf_t(e2); pv[3] = f2bf_t(e3);
            *(short4v*)&myP[lr * 68 + st * 16 + quad * 4] = pv;
        }
        rs += __shfl_xor(rs, 16);
        rs += __shfl_xor(rs, 32);
        l_r = l_r * aa + rs;
        float al_[4];
        #pragma unroll
        for (int r = 0; r < 4; ++r) al_[r] = __shfl(aa, quad * 4 + r);
        #pragma unroll
        for (int nd = 0; nd < 4; ++nd)
            #pragma unroll
            for (int r = 0; r < 4; ++r)
                O[nd][r] *= al_[r];
        // ---- PV: A = P from LDS (same-wave RAW, compiler-ordered) ----
        bf16x8 pf[2];
        #pragma unroll
        for (int kk = 0; kk < 2; ++kk)
            pf[kk] = *(const bf16x8*)&myP[lr * 68 + kk * 32 + quad * 8];
        #pragma unroll
        for (int nd = 0; nd < 4; ++nd)
            #pragma unroll
            for (int kk = 0; kk < 2; ++kk)
                O[nd] = MFMA16(pf[kk], vf[nd][kk], O[nd]);
    }
    // ---- epilogue: normalize and write ctx bf16 directly ----
    float linv[4];
    #pragma unroll
    for (int r = 0; r < 4; ++r) linv[r] = RCPF(__shfl(l_r, quad * 4 + r));
    #pragma unroll
    for (int r = 0; r < 4; ++r) {
        int row = row0 + quad * 4 + r;
        #pragma unroll
        for (int nd = 0; nd < 4; ++nd)
            ctxhi[((size_t)b * SS + row) * EE + h * DD + nd * 16 + lr] =
                f2bf(O[nd][r] * linv[r]);
    }
}

extern "C" void kernel_launch(void* const* d_in, const int* in_sizes, int n_in,
                              void* d_out, int out_size, void* d_ws, size_t ws_size,
                              hipStream_t stream) {
    const float* x     = (const float*)d_in[0];
    const float* Wq    = (const float*)d_in[1];
    const float* bq    = (const float*)d_in[2];
    const float* Wk    = (const float*)d_in[3];
    const float* bk    = (const float*)d_in[4];
    const float* Wv    = (const float*)d_in[5];
    const float* bv    = (const float*)d_in[6];
    const float* Wo    = (const float*)d_in[7];
    const float* bo    = (const float*)d_in[8];
    const float* alpha = (const float*)d_in[9];
    float* out = (float*)d_out;
    char* ws = (char*)d_ws;

    const int M = BB * SS;                 // 4096
    const size_t MB = 1u << 20;
    unsigned short* xhi  = (unsigned short*)(ws + 0 * MB);   // later: ctxhi
    unsigned short* xlo  = (unsigned short*)(ws + 8 * MB);
    unsigned short* Whi  = (unsigned short*)(ws + 16 * MB);  // 6 MB (qkv concat)
    unsigned short* Wlo  = (unsigned short*)(ws + 22 * MB);  // 4 MB used (q,k)
    unsigned short* vt   = (unsigned short*)(ws + 16 * MB);  // reuses dead W area
    unsigned short* Wohi = (unsigned short*)(ws + 28 * MB);
    unsigned short* qhi  = (unsigned short*)(ws + 32 * MB);
    unsigned short* qlo  = (unsigned short*)(ws + 40 * MB);
    unsigned short* khi  = (unsigned short*)(ws + 48 * MB);
    unsigned short* v_sd = (unsigned short*)(ws + 64 * MB);  // dead after transpose
    float* sqn = (float*)(ws + 80 * MB);
    float* skn = (float*)(ws + 80 * MB + 256 * 1024);
    unsigned short* ctxhi = xhi;

    const int nX = M * EE / 4, nW = EE * EE / 4;
    split_f32<<<nX / 256, 256, 0, stream>>>(x, xhi, xlo, nX);
    split_w4<<<dim3(nW / 256, 4), 256, 0, stream>>>(Wq, Wk, Wv, Wo, Whi, Wlo, Wohi);

    // Q/K projections: 3-pass (K=1024 — 2-pass would inject ~0.03 into q/k)
    gemm3p<1, 3><<<dim3(2 * EE / 128, M / 128), 256, 0, stream>>>(
        xhi, xlo, Whi, Wlo, bq, bk, nullptr, nullptr,
        qhi, qlo, khi, nullptr, sqn, skn, M, 2 * EE, EE);
    // V projection: plain bf16 (consumed as bf16 anyway)
    gemm3p<2, 1><<<dim3(EE / 128, M / 128), 256, 0, stream>>>(
        xhi, nullptr, Whi + 2 * (size_t)EE * EE, nullptr, nullptr, nullptr, bv, nullptr,
        nullptr, nullptr, nullptr, v_sd, nullptr, nullptr, M, EE, EE);

    transpose_v<<<dim3(SS / 64, BB * HH), 256, 0, stream>>>(v_sd, vt);

    yat_attn_mfma<<<dim3(SS / 64, BB * HH), 256, 0, stream>>>(
        qhi, qlo, khi, vt, sqn, skn, alpha, ctxhi);

    // O projection: plain bf16 (error ~6e-4 ≪ threshold)
    gemm3p<0, 1><<<dim3(EE / 128, M / 128), 256, 0, stream>>>(
        ctxhi, nullptr, Wohi, nullptr, bo, nullptr, nullptr, out,
        nullptr, nullptr, nullptr, nullptr, nullptr, nullptr, M, EE, EE);
}

// Round 15
// 357.305 us; speedup vs baseline: 1.2425x; 1.2425x over previous
//
#include <hip/hip_runtime.h>
#include <hip/hip_fp16.h>
#include <math.h>

#define BB 2
#define SS 2048
#define EE 1024
#define HH 16
#define DD 64
#define YAT_EPS 1e-5f
#define RR (BB * HH * SS)   // 65536 attention rows

typedef __attribute__((ext_vector_type(8))) short bf16x8;
typedef __attribute__((ext_vector_type(4))) short short4v;
typedef __attribute__((ext_vector_type(4))) float f32x4;
#define MFMA16(a, b, c) __builtin_amdgcn_mfma_f32_16x16x32_bf16((a), (b), (c), 0, 0, 0)

#if __has_builtin(__builtin_amdgcn_exp2f)
#define EXP2(x) __builtin_amdgcn_exp2f(x)
#else
#define EXP2(x) exp2f(x)
#endif
#if __has_builtin(__builtin_amdgcn_rcpf)
#define RCPF(x) __builtin_amdgcn_rcpf(x)
#else
#define RCPF(x) (1.0f / (x))
#endif

__device__ __forceinline__ unsigned short f2bf(float x) {
    unsigned int u = __float_as_uint(x);
    u += 0x7FFFu + ((u >> 16) & 1u);   // RNE
    return (unsigned short)(u >> 16);
}
__device__ __forceinline__ float bf2f(unsigned short h) {
    return __uint_as_float(((unsigned int)h) << 16);
}
// truncating fp32->bf16 (1 op; P in [0,1], bias ~0.1% — renorm-safe)
__device__ __forceinline__ short f2bf_t(float x) {
    return (short)(__float_as_uint(x) >> 16);
}

__device__ __forceinline__ void async_ld16(void* lds, const void* g) {
    __builtin_amdgcn_global_load_lds(
        (const __attribute__((address_space(1))) unsigned int*)g,
        (__attribute__((address_space(3))) unsigned int*)lds, 16, 0, 0);
}

// fp32 -> bf16 hi/lo split (grid covers n/4 float4s exactly)
__global__ __launch_bounds__(256) void split_f32(const float* __restrict__ in,
                                                 unsigned short* __restrict__ hi,
                                                 unsigned short* __restrict__ lo,
                                                 int n4) {
    int i = blockIdx.x * 256 + threadIdx.x;
    if (i >= n4) return;
    float4 v = ((const float4*)in)[i];
    ushort4 h, l;
    h.x = f2bf(v.x); l.x = f2bf(v.x - bf2f(h.x));
    h.y = f2bf(v.y); l.y = f2bf(v.y - bf2f(h.y));
    h.z = f2bf(v.z); l.z = f2bf(v.z - bf2f(h.z));
    h.w = f2bf(v.w); l.w = f2bf(v.w - bf2f(h.w));
    ((ushort4*)hi)[i] = h;
    ((ushort4*)lo)[i] = l;
}

// fused hi/lo split of the four weight matrices; lo only needed for Wq,Wk
__global__ __launch_bounds__(256) void split_w4(
        const float* __restrict__ Wq, const float* __restrict__ Wk,
        const float* __restrict__ Wv, const float* __restrict__ Wo,
        unsigned short* __restrict__ Whi, unsigned short* __restrict__ Wlo,
        unsigned short* __restrict__ Wohi) {
    int i = blockIdx.x * 256 + threadIdx.x;      // < EE*EE/4
    int y = blockIdx.y;
    const float* src = y == 0 ? Wq : y == 1 ? Wk : y == 2 ? Wv : Wo;
    unsigned short* hi = y < 3 ? Whi + (size_t)y * EE * EE : Wohi;
    float4 v = ((const float4*)src)[i];
    ushort4 h;
    h.x = f2bf(v.x); h.y = f2bf(v.y); h.z = f2bf(v.z); h.w = f2bf(v.w);
    ((ushort4*)hi)[i] = h;
    if (y < 2) {
        unsigned short* lo = Wlo + (size_t)y * EE * EE;
        ushort4 l;
        l.x = f2bf(v.x - bf2f(h.x));
        l.y = f2bf(v.y - bf2f(h.y));
        l.z = f2bf(v.z - bf2f(h.z));
        l.w = f2bf(v.w - bf2f(h.w));
        ((ushort4*)lo)[i] = l;
    }
}

// bf16 MFMA GEMM, PASSES=3 (hi/lo Markidis) or 1 (plain bf16).
// C[M,N] = A[M,K] @ B[N,K]^T + bias.
// MODE 0: fp32 out + bias(bq).
// MODE 1: q/k epilogue (N=2048): bf16 hi(+lo for q) [B,H,S,D] + fp32 norms.
// MODE 2: v epilogue (N=1024): bf16 [B,H,S,D], bias in bv.
template <int MODE, int PASSES>
__global__ __launch_bounds__(256, 2) void gemm3p(
        const unsigned short* __restrict__ Ahi, const unsigned short* __restrict__ Alo,
        const unsigned short* __restrict__ Bhi, const unsigned short* __restrict__ Blo,
        const float* __restrict__ bq, const float* __restrict__ bk,
        const float* __restrict__ bv,
        float* __restrict__ Cf,
        unsigned short* __restrict__ qhi, unsigned short* __restrict__ qlo,
        unsigned short* __restrict__ khi,
        unsigned short* __restrict__ v_sd,
        float* __restrict__ sqn, float* __restrict__ skn,
        int M, int N, int K) {
    __shared__ __align__(16) unsigned short LA_hi[128 * 32];
    __shared__ __align__(16) unsigned short LA_lo[128 * 32];
    __shared__ __align__(16) unsigned short LB_hi[128 * 32];
    __shared__ __align__(16) unsigned short LB_lo[128 * 32];

    const int t = threadIdx.x;
    const int w = t >> 6, lane = t & 63;
    const int quad = lane >> 4, lr = lane & 15;
    const int wy = w & 1, wx = w >> 1;
    const int m0 = blockIdx.y * 128, n0 = blockIdx.x * 128;

    const unsigned short* gsrc = nullptr;
    unsigned short* ldst = nullptr;
    if (w == 0)      { gsrc = Ahi + (size_t)m0 * K; ldst = LA_hi; }
    else if (w == 2) { gsrc = Bhi + (size_t)n0 * K; ldst = LB_hi; }
    else if (PASSES == 3 && w == 1) { gsrc = Alo + (size_t)m0 * K; ldst = LA_lo; }
    else if (PASSES == 3 && w == 3) { gsrc = Blo + (size_t)n0 * K; ldst = LB_lo; }
    const unsigned short* gl = gsrc ? gsrc + (size_t)(lane >> 2) * K + (lane & 3) * 8
                                    : nullptr;

    f32x4 acc[4][4];
    #pragma unroll
    for (int i = 0; i < 4; ++i)
        #pragma unroll
        for (int j = 0; j < 4; ++j)
            acc[i][j] = (f32x4){0.f, 0.f, 0.f, 0.f};

    for (int k0 = 0; k0 < K; k0 += 32) {
        __syncthreads();
        if (gl) {
            #pragma unroll
            for (int i = 0; i < 8; ++i)
                async_ld16(ldst + i * 512, gl + (size_t)i * 16 * K + k0);
        }
        __syncthreads();
        bf16x8 ah[4], al[4], bh_[4], bl_[4];
        #pragma unroll
        for (int i = 0; i < 4; ++i) {
            ah[i]  = *(const bf16x8*)&LA_hi[(wy * 64 + i * 16 + lr) * 32 + quad * 8];
            bh_[i] = *(const bf16x8*)&LB_hi[(wx * 64 + i * 16 + lr) * 32 + quad * 8];
            if (PASSES == 3) {
                al[i]  = *(const bf16x8*)&LA_lo[(wy * 64 + i * 16 + lr) * 32 + quad * 8];
                bl_[i] = *(const bf16x8*)&LB_lo[(wx * 64 + i * 16 + lr) * 32 + quad * 8];
            }
        }
        #pragma unroll
        for (int mg = 0; mg < 4; ++mg)
            #pragma unroll
            for (int ns = 0; ns < 4; ++ns) {
                f32x4 a = acc[mg][ns];
                a = MFMA16(ah[mg], bh_[ns], a);
                if (PASSES == 3) {
                    a = MFMA16(ah[mg], bl_[ns], a);
                    a = MFMA16(al[mg], bh_[ns], a);
                }
                acc[mg][ns] = a;
            }
    }

    const int ng = n0 + wx * 64;
    if (MODE == 0) {
        float bias_v[4];
        #pragma unroll
        for (int ns = 0; ns < 4; ++ns) bias_v[ns] = bq[ng + ns * 16 + lr];
        #pragma unroll
        for (int mg = 0; mg < 4; ++mg)
            #pragma unroll
            for (int r = 0; r < 4; ++r) {
                int m = m0 + wy * 64 + mg * 16 + quad * 4 + r;
                #pragma unroll
                for (int ns = 0; ns < 4; ++ns)
                    Cf[(size_t)m * N + ng + ns * 16 + lr] = acc[mg][ns][r] + bias_v[ns];
            }
    } else {
        const int path = MODE == 1 ? (ng >> 10) : 2;   // 0=q 1=k 2=v
        const int c = MODE == 1 ? (ng & 1023) : ng;
        const int h = c >> 6;
        const float* bias = path == 0 ? bq : path == 1 ? bk : bv;
        unsigned short* hi_p = path == 0 ? qhi : path == 1 ? khi : v_sd;
        float* nrm = path == 0 ? sqn : skn;
        float bias_v[4];
        #pragma unroll
        for (int ns = 0; ns < 4; ++ns) bias_v[ns] = bias[c + ns * 16 + lr];
        #pragma unroll
        for (int mg = 0; mg < 4; ++mg)
            #pragma unroll
            for (int r = 0; r < 4; ++r) {
                int m = m0 + wy * 64 + mg * 16 + quad * 4 + r;
                int b = m >> 11, s = m & (SS - 1);
                size_t base = ((size_t)(b * HH + h) * SS + s) * DD;
                float v4[4];
                #pragma unroll
                for (int ns = 0; ns < 4; ++ns) v4[ns] = acc[mg][ns][r] + bias_v[ns];
                if (path < 2) {
                    float pn = v4[0] * v4[0] + v4[1] * v4[1] + v4[2] * v4[2] + v4[3] * v4[3];
                    #pragma unroll
                    for (int off = 1; off < 16; off <<= 1) pn += __shfl_xor(pn, off);
                    if (lr == 0) nrm[(size_t)(b * HH + h) * SS + s] = pn;
                    #pragma unroll
                    for (int ns = 0; ns < 4; ++ns) {
                        unsigned short hv = f2bf(v4[ns]);
                        hi_p[base + ns * 16 + lr] = hv;
                        if (path == 0)
                            qlo[base + ns * 16 + lr] = f2bf(v4[ns] - bf2f(hv));
                    }
                } else {
                    #pragma unroll
                    for (int ns = 0; ns < 4; ++ns)
                        hi_p[base + ns * 16 + lr] = f2bf(v4[ns]);
                }
            }
    }
}

// [bh][s][d] -> [bh][d][s] bf16 transpose, 64x64 LDS tiles
__global__ __launch_bounds__(256) void transpose_v(const unsigned short* __restrict__ v_sd,
                                                   unsigned short* __restrict__ vt) {
    __shared__ unsigned short T[64][65];
    const int t = threadIdx.x;
    const int bh = blockIdx.y, s0 = blockIdx.x * 64;
    {
        int sl = t >> 2, d4 = (t & 3) * 16;
        const unsigned short* src = &v_sd[((size_t)bh * SS + s0 + sl) * DD + d4];
        bf16x8 a = *(const bf16x8*)src;
        bf16x8 b = *(const bf16x8*)(src + 8);
        #pragma unroll
        for (int j = 0; j < 8; ++j) {
            T[sl][d4 + j] = (unsigned short)a[j];
            T[sl][d4 + 8 + j] = (unsigned short)b[j];
        }
    }
    __syncthreads();
    {
        int dl = t >> 2, s4 = (t & 3) * 16;
        bf16x8 a, b;
        #pragma unroll
        for (int j = 0; j < 8; ++j) {
            a[j] = (short)T[s4 + j][dl];
            b[j] = (short)T[s4 + 8 + j][dl];
        }
        unsigned short* dst = &vt[((size_t)bh * DD + dl) * SS + s0 + s4];
        *(bf16x8*)dst = a;
        *(bf16x8*)(dst + 8) = b;
    }
}

// MFMA flash attention v9: r11 structure (best measured: LDS-staged K,
// K-split x2, one barrier per staging step) with two surgical mods:
//  (1) BK=128 — two 64-k-tiles per barrier: halves the 32 barrier/vmcnt(0)
//      drains to 16. LDS 49.4KB -> still 3 blocks/CU (register-bound at 3).
//  (2) u-domain softmax (r13-validated VALU cut): max tracked in u=qk^2/d,
//      cscale applied only inside the exp fma; mlpart.x stores cscale*m so
//      the combine kernel is unchanged.
// r12's SWP, r13's grid shrink, r14's barrier-free form all regressed — this
// stays on the measured-best structure.
__global__ __launch_bounds__(256, 3) void yat_attn_mfma(
        const unsigned short* __restrict__ qhi, const unsigned short* __restrict__ qlo,
        const unsigned short* __restrict__ khi,
        const unsigned short* __restrict__ vt,
        const float* __restrict__ sqn, const float* __restrict__ skn,
        const float* __restrict__ alphap,
        __half* __restrict__ Opart, float2* __restrict__ mlpart) {
    __shared__ __align__(16) unsigned short Ks[2][8192];        // [dbuf][2 tiles khi] 32KB
    __shared__ __align__(16) unsigned short Ps[2][4][16 * 68];  // [dbuf][wave] 17.4KB

    const int t = threadIdx.x;
    const int w = t >> 6, lane = t & 63;
    const int quad = lane >> 4, lr = lane & 15;
    const int qt = blockIdx.x, bh = blockIdx.y, z = blockIdx.z;
    const int row0 = qt * 64 + w * 16;
    // exp2-domain softmax; max tracked in u = qk^2/d (monotone under cscale>0)
    const float cscale = powf(sqrtf((float)DD) / log1pf((float)DD), alphap[0])
                         * 1.4426950408889634f;

    // persistent Q fragments (B-operand: lane holds q-col = lr)
    bf16x8 qh[2], ql[2];
    #pragma unroll
    for (int kd = 0; kd < 2; ++kd) {
        size_t o = ((size_t)bh * SS + row0 + lr) * DD + kd * 32 + quad * 8;
        qh[kd] = *(const bf16x8*)&qhi[o];
        ql[kd] = *(const bf16x8*)&qlo[o];
    }
    const float sqe = sqn[(size_t)bh * SS + row0 + lr] + YAT_EPS;

    // staging: wave w stages rows [w*16,w*16+16) of each khi tile; XOR-swizzled
    const int lrow = lane >> 3;
    const int lofs = lrow * 64 + (((lane & 7) ^ (lrow & 7)) << 3);
    const int sw = lr & 15 & 7;

    float m_r = -INFINITY, l_r = 0.f;   // m_r in u-domain
    f32x4 O[4];
    #pragma unroll
    for (int nd = 0; nd < 4; ++nd) O[nd] = (f32x4){0.f, 0.f, 0.f, 0.f};

    const int t0 = z * 16;              // first 64-row tile index for this split
    const size_t khi_base = (size_t)bh * SS * 64 + (size_t)w * 16 * 64 + lofs;
    const size_t skn_base = (size_t)bh * SS + quad * 4;

    // prologue: stage tiles t0, t0+1 into buf 0
    #pragma unroll
    for (int tl = 0; tl < 2; ++tl)
        #pragma unroll
        for (int i2 = 0; i2 < 2; ++i2)
            async_ld16(&Ks[0][tl * 4096 + w * 1024 + i2 * 512],
                       khi + khi_base + (size_t)(t0 + tl) * 4096 + i2 * 512);

    for (int it = 0; it < 8; ++it) {
        const int p = it & 1;
        __syncthreads();   // drains async stage of buf[p]
        if (it + 1 < 8) {  // prefetch next 2 tiles into buf[p^1]
            #pragma unroll
            for (int tl = 0; tl < 2; ++tl)
                #pragma unroll
                for (int i2 = 0; i2 < 2; ++i2)
                    async_ld16(&Ks[p ^ 1][tl * 4096 + w * 1024 + i2 * 512],
                               khi + khi_base
                                   + (size_t)(t0 + 2 * (it + 1) + tl) * 4096
                                   + i2 * 512);
        }
        #pragma unroll
        for (int sub = 0; sub < 2; ++sub) {
            const int kbase = (t0 + 2 * it + sub) * 64;
            const unsigned short* kb = &Ks[p][sub * 4096];
            // ---- QK'^T = K.(qh+ql)^T from LDS (2-pass) ----
            f32x4 acc[4];
            f32x4 sk4[4];
            #pragma unroll
            for (int st = 0; st < 4; ++st) {
                const int rbase = (st * 16 + lr) * 64;
                bf16x8 kh0 = *(const bf16x8*)&kb[rbase + ((quad    ) ^ sw) * 8];
                bf16x8 kh1 = *(const bf16x8*)&kb[rbase + ((quad + 4) ^ sw) * 8];
                sk4[st] = *(const f32x4*)&skn[skn_base + kbase + st * 16];
                f32x4 a = (f32x4){0.f, 0.f, 0.f, 0.f};
                a = MFMA16(kh0, qh[0], a);
                a = MFMA16(kh1, qh[1], a);
                a = MFMA16(kh0, ql[0], a);
                a = MFMA16(kh1, ql[1], a);
                acc[st] = a;
            }
            // ---- V fragments (global; issue early to overlap softmax) ----
            bf16x8 vf[4][2];
            #pragma unroll
            for (int nd = 0; nd < 4; ++nd)
                #pragma unroll
                for (int kk = 0; kk < 2; ++kk)
                    vf[nd][kk] = *(const bf16x8*)&vt[((size_t)bh * DD + nd * 16 + lr) * SS
                                                     + kbase + kk * 32 + quad * 8];
            // ---- softmax: u = qk^2/d in place, max in u-domain ----
            float mx = -INFINITY;
            #pragma unroll
            for (int st = 0; st < 4; ++st)
                #pragma unroll
                for (int r = 0; r < 4; ++r) {
                    float qk = acc[st][r];
                    float d = sqe + sk4[st][r] - 2.f * qk;
                    float u = qk * qk * RCPF(d);
                    acc[st][r] = u;
                    mx = fmaxf(mx, u);
                }
            mx = fmaxf(mx, __shfl_xor(mx, 16));
            mx = fmaxf(mx, __shfl_xor(mx, 32));
            float mnew = fmaxf(m_r, mx);
            float cm = cscale * mnew;
            float aa = EXP2(__builtin_fmaf(cscale, m_r, -cm));
            m_r = mnew;
            unsigned short* myP = Ps[p][w];
            float rs = 0.f;
            #pragma unroll
            for (int st = 0; st < 4; ++st) {
                float e0 = EXP2(__builtin_fmaf(cscale, acc[st][0], -cm));
                float e1 = EXP2(__builtin_fmaf(cscale, acc[st][1], -cm));
                float e2 = EXP2(__builtin_fmaf(cscale, acc[st][2], -cm));
                float e3 = EXP2(__builtin_fmaf(cscale, acc[st][3], -cm));
                rs += (e0 + e1) + (e2 + e3);
                short4v pv;
                pv[0] = f2bf_t(e0); pv[1] = f2bf_t(e1);
                pv[2] = f2bf_t(e2); pv[3] = f2bf_t(e3);
                *(short4v*)&myP[lr * 68 + st * 16 + quad * 4] = pv;
            }
            rs += __shfl_xor(rs, 16);
            rs += __shfl_xor(rs, 32);
            l_r = l_r * aa + rs;
            float al_[4];
            #pragma unroll
            for (int r = 0; r < 4; ++r) al_[r] = __shfl(aa, quad * 4 + r);
            #pragma unroll
            for (int nd = 0; nd < 4; ++nd)
                #pragma unroll
                for (int r = 0; r < 4; ++r)
                    O[nd][r] *= al_[r];
            // ---- PV: A = P from LDS (same-wave RAW/WAR, dependence-ordered) ----
            bf16x8 pf[2];
            #pragma unroll
            for (int kk = 0; kk < 2; ++kk)
                pf[kk] = *(const bf16x8*)&myP[lr * 68 + kk * 32 + quad * 8];
            #pragma unroll
            for (int nd = 0; nd < 4; ++nd)
                #pragma unroll
                for (int kk = 0; kk < 2; ++kk)
                    O[nd] = MFMA16(pf[kk], vf[nd][kk], O[nd]);
        }
    }
    // ---- epilogue: write fp16 partial O + (cscale*m, l) ----
    if (quad == 0)
        mlpart[(size_t)z * RR + (size_t)bh * SS + row0 + lr] =
            make_float2(cscale * m_r, l_r);
    #pragma unroll
    for (int r = 0; r < 4; ++r) {
        size_t rowg = (size_t)bh * SS + row0 + quad * 4 + r;
        #pragma unroll
        for (int nd = 0; nd < 4; ++nd)
            Opart[((size_t)z * RR + rowg) * DD + nd * 16 + lr] =
                __float2half(O[nd][r]);
    }
}

// merge K-split halves; write ctx bf16 (hi only — O-proj is plain bf16)
__global__ __launch_bounds__(256) void combine_attn(
        const __half* __restrict__ Opart, const float2* __restrict__ mlpart,
        unsigned short* __restrict__ ctxhi) {
    int tid = blockIdx.x * 256 + threadIdx.x;
    int row = tid >> 4, c4 = (tid & 15) * 4;
    float2 ml0 = mlpart[row];
    float2 ml1 = mlpart[RR + row];
    float ms = fmaxf(ml0.x, ml1.x);
    float a0 = EXP2(ml0.x - ms), a1 = EXP2(ml1.x - ms);
    float inv = RCPF(ml0.y * a0 + ml1.y * a1);
    a0 *= inv; a1 *= inv;
    const __half* p0 = Opart + (size_t)row * DD + c4;
    const __half* p1 = p0 + (size_t)RR * DD;
    int bh = row >> 11, s = row & (SS - 1);
    int b = bh >> 4, h = bh & 15;
    size_t idx = ((size_t)b * SS + s) * EE + h * DD + c4;
    ushort4 hv;
    unsigned short* hp = (unsigned short*)&hv;
    #pragma unroll
    for (int j = 0; j < 4; ++j) {
        float o = __half2float(p0[j]) * a0 + __half2float(p1[j]) * a1;
        hp[j] = f2bf(o);
    }
    *(ushort4*)&ctxhi[idx] = hv;
}

extern "C" void kernel_launch(void* const* d_in, const int* in_sizes, int n_in,
                              void* d_out, int out_size, void* d_ws, size_t ws_size,
                              hipStream_t stream) {
    const float* x     = (const float*)d_in[0];
    const float* Wq    = (const float*)d_in[1];
    const float* bq    = (const float*)d_in[2];
    const float* Wk    = (const float*)d_in[3];
    const float* bk    = (const float*)d_in[4];
    const float* Wv    = (const float*)d_in[5];
    const float* bv    = (const float*)d_in[6];
    const float* Wo    = (const float*)d_in[7];
    const float* bo    = (const float*)d_in[8];
    const float* alpha = (const float*)d_in[9];
    float* out = (float*)d_out;
    char* ws = (char*)d_ws;

    const int M = BB * SS;                 // 4096
    const size_t MB = 1u << 20;
    unsigned short* xhi  = (unsigned short*)(ws + 0 * MB);   // later: ctxhi
    unsigned short* xlo  = (unsigned short*)(ws + 8 * MB);
    unsigned short* Whi  = (unsigned short*)(ws + 16 * MB);  // 6 MB (qkv concat)
    unsigned short* Wlo  = (unsigned short*)(ws + 22 * MB);  // 4 MB used (q,k)
    unsigned short* vt   = (unsigned short*)(ws + 16 * MB);  // reuses dead W area
    float2* mlpart       = (float2*)(ws + 24 * MB);          // 1 MB
    unsigned short* Wohi = (unsigned short*)(ws + 28 * MB);
    unsigned short* qhi  = (unsigned short*)(ws + 32 * MB);
    unsigned short* qlo  = (unsigned short*)(ws + 40 * MB);
    unsigned short* khi  = (unsigned short*)(ws + 48 * MB);
    unsigned short* v_sd = (unsigned short*)(ws + 64 * MB);  // dead after transpose
    __half* Opart        = (__half*)(ws + 64 * MB);          // 16 MB (reuses v_sd)
    float* sqn = (float*)(ws + 80 * MB);
    float* skn = (float*)(ws + 80 * MB + 256 * 1024);
    unsigned short* ctxhi = xhi;

    const int nX = M * EE / 4, nW = EE * EE / 4;
    split_f32<<<nX / 256, 256, 0, stream>>>(x, xhi, xlo, nX);
    split_w4<<<dim3(nW / 256, 4), 256, 0, stream>>>(Wq, Wk, Wv, Wo, Whi, Wlo, Wohi);

    // Q/K projections: 3-pass (K=1024 — 2-pass would inject ~0.03 into q/k)
    gemm3p<1, 3><<<dim3(2 * EE / 128, M / 128), 256, 0, stream>>>(
        xhi, xlo, Whi, Wlo, bq, bk, nullptr, nullptr,
        qhi, qlo, khi, nullptr, sqn, skn, M, 2 * EE, EE);
    // V projection: plain bf16 (consumed as bf16 anyway)
    gemm3p<2, 1><<<dim3(EE / 128, M / 128), 256, 0, stream>>>(
        xhi, nullptr, Whi + 2 * (size_t)EE * EE, nullptr, nullptr, nullptr, bv, nullptr,
        nullptr, nullptr, nullptr, v_sd, nullptr, nullptr, M, EE, EE);

    transpose_v<<<dim3(SS / 64, BB * HH), 256, 0, stream>>>(v_sd, vt);

    yat_attn_mfma<<<dim3(SS / 64, BB * HH, 2), 256, 0, stream>>>(
        qhi, qlo, khi, vt, sqn, skn, alpha, Opart, mlpart);

    combine_attn<<<RR * 16 / 256, 256, 0, stream>>>(Opart, mlpart, ctxhi);

    // O projection: plain bf16 (error ~6e-4 ≪ threshold)
    gemm3p<0, 1><<<dim3(EE / 128, M / 128), 256, 0, stream>>>(
        ctxhi, nullptr, Wohi, nullptr, bo, nullptr, nullptr, out,
        nullptr, nullptr, nullptr, nullptr, nullptr, nullptr, M, EE, EE);
}

// Round 17
// 356.980 us; speedup vs baseline: 1.2437x; 1.0009x over previous
//
#include <hip/hip_runtime.h>
#include <hip/hip_fp16.h>
#include <math.h>

#define BB 2
#define SS 2048
#define EE 1024
#define HH 16
#define DD 64
#define YAT_EPS 1e-5f
#define RR (BB * HH * SS)   // 65536 attention rows

typedef __attribute__((ext_vector_type(8))) short bf16x8;
typedef __attribute__((ext_vector_type(4))) short short4v;
typedef __attribute__((ext_vector_type(4))) float f32x4;
#define MFMA16(a, b, c) __builtin_amdgcn_mfma_f32_16x16x32_bf16((a), (b), (c), 0, 0, 0)

#if __has_builtin(__builtin_amdgcn_exp2f)
#define EXP2(x) __builtin_amdgcn_exp2f(x)
#else
#define EXP2(x) exp2f(x)
#endif
#if __has_builtin(__builtin_amdgcn_rcpf)
#define RCPF(x) __builtin_amdgcn_rcpf(x)
#else
#define RCPF(x) (1.0f / (x))
#endif

__device__ __forceinline__ unsigned short f2bf(float x) {
    unsigned int u = __float_as_uint(x);
    u += 0x7FFFu + ((u >> 16) & 1u);   // RNE
    return (unsigned short)(u >> 16);
}
__device__ __forceinline__ float bf2f(unsigned short h) {
    return __uint_as_float(((unsigned int)h) << 16);
}
// truncating fp32->bf16 (1 op; P in [0,1], bias ~0.1% — renorm-safe)
__device__ __forceinline__ short f2bf_t(float x) {
    return (short)(__float_as_uint(x) >> 16);
}

__device__ __forceinline__ void async_ld16(void* lds, const void* g) {
    __builtin_amdgcn_global_load_lds(
        (const __attribute__((address_space(1))) unsigned int*)g,
        (__attribute__((address_space(3))) unsigned int*)lds, 16, 0, 0);
}

// fp32 -> bf16 hi/lo split (grid covers n/4 float4s exactly)
__global__ __launch_bounds__(256) void split_f32(const float* __restrict__ in,
                                                 unsigned short* __restrict__ hi,
                                                 unsigned short* __restrict__ lo,
                                                 int n4) {
    int i = blockIdx.x * 256 + threadIdx.x;
    if (i >= n4) return;
    float4 v = ((const float4*)in)[i];
    ushort4 h, l;
    h.x = f2bf(v.x); l.x = f2bf(v.x - bf2f(h.x));
    h.y = f2bf(v.y); l.y = f2bf(v.y - bf2f(h.y));
    h.z = f2bf(v.z); l.z = f2bf(v.z - bf2f(h.z));
    h.w = f2bf(v.w); l.w = f2bf(v.w - bf2f(h.w));
    ((ushort4*)hi)[i] = h;
    ((ushort4*)lo)[i] = l;
}

// fused hi/lo split of the four weight matrices; lo only needed for Wq,Wk
__global__ __launch_bounds__(256) void split_w4(
        const float* __restrict__ Wq, const float* __restrict__ Wk,
        const float* __restrict__ Wv, const float* __restrict__ Wo,
        unsigned short* __restrict__ Whi, unsigned short* __restrict__ Wlo,
        unsigned short* __restrict__ Wohi) {
    int i = blockIdx.x * 256 + threadIdx.x;      // < EE*EE/4
    int y = blockIdx.y;
    const float* src = y == 0 ? Wq : y == 1 ? Wk : y == 2 ? Wv : Wo;
    unsigned short* hi = y < 3 ? Whi + (size_t)y * EE * EE : Wohi;
    float4 v = ((const float4*)src)[i];
    ushort4 h;
    h.x = f2bf(v.x); h.y = f2bf(v.y); h.z = f2bf(v.z); h.w = f2bf(v.w);
    ((ushort4*)hi)[i] = h;
    if (y < 2) {
        unsigned short* lo = Wlo + (size_t)y * EE * EE;
        ushort4 l;
        l.x = f2bf(v.x - bf2f(h.x));
        l.y = f2bf(v.y - bf2f(h.y));
        l.z = f2bf(v.z - bf2f(h.z));
        l.w = f2bf(v.w - bf2f(h.w));
        ((ushort4*)lo)[i] = l;
    }
}

// bf16 MFMA GEMM, PASSES=3 (hi/lo Markidis) or 1 (plain bf16).
// C[M,N] = A[M,K] @ B[N,K]^T + bias.
// MODE 0: fp32 out + bias(bq).
// MODE 1: q/k epilogue (N=2048): bf16 hi(+lo for q) [B,H,S,D] + fp32 norms.
// MODE 2: v epilogue (N=1024): bf16 [B,H,S,D], bias in bv.
template <int MODE, int PASSES>
__global__ __launch_bounds__(256, 2) void gemm3p(
        const unsigned short* __restrict__ Ahi, const unsigned short* __restrict__ Alo,
        const unsigned short* __restrict__ Bhi, const unsigned short* __restrict__ Blo,
        const float* __restrict__ bq, const float* __restrict__ bk,
        const float* __restrict__ bv,
        float* __restrict__ Cf,
        unsigned short* __restrict__ qhi, unsigned short* __restrict__ qlo,
        unsigned short* __restrict__ khi,
        unsigned short* __restrict__ v_sd,
        float* __restrict__ sqn, float* __restrict__ skn,
        int M, int N, int K) {
    __shared__ __align__(16) unsigned short LA_hi[128 * 32];
    __shared__ __align__(16) unsigned short LA_lo[128 * 32];
    __shared__ __align__(16) unsigned short LB_hi[128 * 32];
    __shared__ __align__(16) unsigned short LB_lo[128 * 32];

    const int t = threadIdx.x;
    const int w = t >> 6, lane = t & 63;
    const int quad = lane >> 4, lr = lane & 15;
    const int wy = w & 1, wx = w >> 1;
    const int m0 = blockIdx.y * 128, n0 = blockIdx.x * 128;

    const unsigned short* gsrc = nullptr;
    unsigned short* ldst = nullptr;
    if (w == 0)      { gsrc = Ahi + (size_t)m0 * K; ldst = LA_hi; }
    else if (w == 2) { gsrc = Bhi + (size_t)n0 * K; ldst = LB_hi; }
    else if (PASSES == 3 && w == 1) { gsrc = Alo + (size_t)m0 * K; ldst = LA_lo; }
    else if (PASSES == 3 && w == 3) { gsrc = Blo + (size_t)n0 * K; ldst = LB_lo; }
    const unsigned short* gl = gsrc ? gsrc + (size_t)(lane >> 2) * K + (lane & 3) * 8
                                    : nullptr;

    f32x4 acc[4][4];
    #pragma unroll
    for (int i = 0; i < 4; ++i)
        #pragma unroll
        for (int j = 0; j < 4; ++j)
            acc[i][j] = (f32x4){0.f, 0.f, 0.f, 0.f};

    for (int k0 = 0; k0 < K; k0 += 32) {
        __syncthreads();
        if (gl) {
            #pragma unroll
            for (int i = 0; i < 8; ++i)
                async_ld16(ldst + i * 512, gl + (size_t)i * 16 * K + k0);
        }
        __syncthreads();
        bf16x8 ah[4], al[4], bh_[4], bl_[4];
        #pragma unroll
        for (int i = 0; i < 4; ++i) {
            ah[i]  = *(const bf16x8*)&LA_hi[(wy * 64 + i * 16 + lr) * 32 + quad * 8];
            bh_[i] = *(const bf16x8*)&LB_hi[(wx * 64 + i * 16 + lr) * 32 + quad * 8];
            if (PASSES == 3) {
                al[i]  = *(const bf16x8*)&LA_lo[(wy * 64 + i * 16 + lr) * 32 + quad * 8];
                bl_[i] = *(const bf16x8*)&LB_lo[(wx * 64 + i * 16 + lr) * 32 + quad * 8];
            }
        }
        #pragma unroll
        for (int mg = 0; mg < 4; ++mg)
            #pragma unroll
            for (int ns = 0; ns < 4; ++ns) {
                f32x4 a = acc[mg][ns];
                a = MFMA16(ah[mg], bh_[ns], a);
                if (PASSES == 3) {
                    a = MFMA16(ah[mg], bl_[ns], a);
                    a = MFMA16(al[mg], bh_[ns], a);
                }
                acc[mg][ns] = a;
            }
    }

    const int ng = n0 + wx * 64;
    if (MODE == 0) {
        float bias_v[4];
        #pragma unroll
        for (int ns = 0; ns < 4; ++ns) bias_v[ns] = bq[ng + ns * 16 + lr];
        #pragma unroll
        for (int mg = 0; mg < 4; ++mg)
            #pragma unroll
            for (int r = 0; r < 4; ++r) {
                int m = m0 + wy * 64 + mg * 16 + quad * 4 + r;
                #pragma unroll
                for (int ns = 0; ns < 4; ++ns)
                    Cf[(size_t)m * N + ng + ns * 16 + lr] = acc[mg][ns][r] + bias_v[ns];
            }
    } else {
        const int path = MODE == 1 ? (ng >> 10) : 2;   // 0=q 1=k 2=v
        const int c = MODE == 1 ? (ng & 1023) : ng;
        const int h = c >> 6;
        const float* bias = path == 0 ? bq : path == 1 ? bk : bv;
        unsigned short* hi_p = path == 0 ? qhi : path == 1 ? khi : v_sd;
        float* nrm = path == 0 ? sqn : skn;
        float bias_v[4];
        #pragma unroll
        for (int ns = 0; ns < 4; ++ns) bias_v[ns] = bias[c + ns * 16 + lr];
        #pragma unroll
        for (int mg = 0; mg < 4; ++mg)
            #pragma unroll
            for (int r = 0; r < 4; ++r) {
                int m = m0 + wy * 64 + mg * 16 + quad * 4 + r;
                int b = m >> 11, s = m & (SS - 1);
                size_t base = ((size_t)(b * HH + h) * SS + s) * DD;
                float v4[4];
                #pragma unroll
                for (int ns = 0; ns < 4; ++ns) v4[ns] = acc[mg][ns][r] + bias_v[ns];
                if (path < 2) {
                    float pn = v4[0] * v4[0] + v4[1] * v4[1] + v4[2] * v4[2] + v4[3] * v4[3];
                    #pragma unroll
                    for (int off = 1; off < 16; off <<= 1) pn += __shfl_xor(pn, off);
                    if (lr == 0) nrm[(size_t)(b * HH + h) * SS + s] = pn;
                    #pragma unroll
                    for (int ns = 0; ns < 4; ++ns) {
                        unsigned short hv = f2bf(v4[ns]);
                        hi_p[base + ns * 16 + lr] = hv;
                        if (path == 0)
                            qlo[base + ns * 16 + lr] = f2bf(v4[ns] - bf2f(hv));
                    }
                } else {
                    #pragma unroll
                    for (int ns = 0; ns < 4; ++ns)
                        hi_p[base + ns * 16 + lr] = f2bf(v4[ns]);
                }
            }
    }
}

// [bh][s][d] -> [bh][d][s] bf16 transpose, 64x64 LDS tiles
__global__ __launch_bounds__(256) void transpose_v(const unsigned short* __restrict__ v_sd,
                                                   unsigned short* __restrict__ vt) {
    __shared__ unsigned short T[64][65];
    const int t = threadIdx.x;
    const int bh = blockIdx.y, s0 = blockIdx.x * 64;
    {
        int sl = t >> 2, d4 = (t & 3) * 16;
        const unsigned short* src = &v_sd[((size_t)bh * SS + s0 + sl) * DD + d4];
        bf16x8 a = *(const bf16x8*)src;
        bf16x8 b = *(const bf16x8*)(src + 8);
        #pragma unroll
        for (int j = 0; j < 8; ++j) {
            T[sl][d4 + j] = (unsigned short)a[j];
            T[sl][d4 + 8 + j] = (unsigned short)b[j];
        }
    }
    __syncthreads();
    {
        int dl = t >> 2, s4 = (t & 3) * 16;
        bf16x8 a, b;
        #pragma unroll
        for (int j = 0; j < 8; ++j) {
            a[j] = (short)T[s4 + j][dl];
            b[j] = (short)T[s4 + 8 + j][dl];
        }
        unsigned short* dst = &vt[((size_t)bh * DD + dl) * SS + s0 + s4];
        *(bf16x8*)dst = a;
        *(bf16x8*)(dst + 8) = b;
    }
}

// MFMA flash attention v9 (round-15 measured best, restored verbatim):
// LDS-staged K (BK=128, double-buffered async global_load_lds, XOR-swizzle),
// K-split x2, 2-pass QK (khi only), u-domain softmax, per-wave P slices.
__global__ __launch_bounds__(256, 3) void yat_attn_mfma(
        const unsigned short* __restrict__ qhi, const unsigned short* __restrict__ qlo,
        const unsigned short* __restrict__ khi,
        const unsigned short* __restrict__ vt,
        const float* __restrict__ sqn, const float* __restrict__ skn,
        const float* __restrict__ alphap,
        __half* __restrict__ Opart, float2* __restrict__ mlpart) {
    __shared__ __align__(16) unsigned short Ks[2][8192];        // [dbuf][2 tiles khi] 32KB
    __shared__ __align__(16) unsigned short Ps[2][4][16 * 68];  // [dbuf][wave] 17.4KB

    const int t = threadIdx.x;
    const int w = t >> 6, lane = t & 63;
    const int quad = lane >> 4, lr = lane & 15;
    const int qt = blockIdx.x, bh = blockIdx.y, z = blockIdx.z;
    const int row0 = qt * 64 + w * 16;
    const float cscale = powf(sqrtf((float)DD) / log1pf((float)DD), alphap[0])
                         * 1.4426950408889634f;

    bf16x8 qh[2], ql[2];
    #pragma unroll
    for (int kd = 0; kd < 2; ++kd) {
        size_t o = ((size_t)bh * SS + row0 + lr) * DD + kd * 32 + quad * 8;
        qh[kd] = *(const bf16x8*)&qhi[o];
        ql[kd] = *(const bf16x8*)&qlo[o];
    }
    const float sqe = sqn[(size_t)bh * SS + row0 + lr] + YAT_EPS;

    const int lrow = lane >> 3;
    const int lofs = lrow * 64 + (((lane & 7) ^ (lrow & 7)) << 3);
    const int sw = lr & 7;

    float m_r = -INFINITY, l_r = 0.f;   // m_r in u-domain
    f32x4 O[4];
    #pragma unroll
    for (int nd = 0; nd < 4; ++nd) O[nd] = (f32x4){0.f, 0.f, 0.f, 0.f};

    const int t0 = z * 16;
    const size_t khi_base = (size_t)bh * SS * 64 + (size_t)w * 16 * 64 + lofs;
    const size_t skn_base = (size_t)bh * SS + quad * 4;

    #pragma unroll
    for (int tl = 0; tl < 2; ++tl)
        #pragma unroll
        for (int i2 = 0; i2 < 2; ++i2)
            async_ld16(&Ks[0][tl * 4096 + w * 1024 + i2 * 512],
                       khi + khi_base + (size_t)(t0 + tl) * 4096 + i2 * 512);

    for (int it = 0; it < 8; ++it) {
        const int p = it & 1;
        __syncthreads();
        if (it + 1 < 8) {
            #pragma unroll
            for (int tl = 0; tl < 2; ++tl)
                #pragma unroll
                for (int i2 = 0; i2 < 2; ++i2)
                    async_ld16(&Ks[p ^ 1][tl * 4096 + w * 1024 + i2 * 512],
                               khi + khi_base
                                   + (size_t)(t0 + 2 * (it + 1) + tl) * 4096
                                   + i2 * 512);
        }
        #pragma unroll
        for (int sub = 0; sub < 2; ++sub) {
            const int kbase = (t0 + 2 * it + sub) * 64;
            const unsigned short* kb = &Ks[p][sub * 4096];
            f32x4 acc[4];
            f32x4 sk4[4];
            #pragma unroll
            for (int st = 0; st < 4; ++st) {
                const int rbase = (st * 16 + lr) * 64;
                bf16x8 kh0 = *(const bf16x8*)&kb[rbase + ((quad    ) ^ sw) * 8];
                bf16x8 kh1 = *(const bf16x8*)&kb[rbase + ((quad + 4) ^ sw) * 8];
                sk4[st] = *(const f32x4*)&skn[skn_base + kbase + st * 16];
                f32x4 a = (f32x4){0.f, 0.f, 0.f, 0.f};
                a = MFMA16(kh0, qh[0], a);
                a = MFMA16(kh1, qh[1], a);
                a = MFMA16(kh0, ql[0], a);
                a = MFMA16(kh1, ql[1], a);
                acc[st] = a;
            }
            bf16x8 vf[4][2];
            #pragma unroll
            for (int nd = 0; nd < 4; ++nd)
                #pragma unroll
                for (int kk = 0; kk < 2; ++kk)
                    vf[nd][kk] = *(const bf16x8*)&vt[((size_t)bh * DD + nd * 16 + lr) * SS
                                                     + kbase + kk * 32 + quad * 8];
            float mx = -INFINITY;
            #pragma unroll
            for (int st = 0; st < 4; ++st)
                #pragma unroll
                for (int r = 0; r < 4; ++r) {
                    float qk = acc[st][r];
                    float d = sqe + sk4[st][r] - 2.f * qk;
                    float u = qk * qk * RCPF(d);
                    acc[st][r] = u;
                    mx = fmaxf(mx, u);
                }
            mx = fmaxf(mx, __shfl_xor(mx, 16));
            mx = fmaxf(mx, __shfl_xor(mx, 32));
            float mnew = fmaxf(m_r, mx);
            float cm = cscale * mnew;
            float aa = EXP2(__builtin_fmaf(cscale, m_r, -cm));
            m_r = mnew;
            unsigned short* myP = Ps[p][w];
            float rs = 0.f;
            #pragma unroll
            for (int st = 0; st < 4; ++st) {
                float e0 = EXP2(__builtin_fmaf(cscale, acc[st][0], -cm));
                float e1 = EXP2(__builtin_fmaf(cscale, acc[st][1], -cm));
                float e2 = EXP2(__builtin_fmaf(cscale, acc[st][2], -cm));
                float e3 = EXP2(__builtin_fmaf(cscale, acc[st][3], -cm));
                rs += (e0 + e1) + (e2 + e3);
                short4v pv;
                pv[0] = f2bf_t(e0); pv[1] = f2bf_t(e1);
                pv[2] = f2bf_t(e2); pv[3] = f2bf_t(e3);
                *(short4v*)&myP[lr * 68 + st * 16 + quad * 4] = pv;
            }
            rs += __shfl_xor(rs, 16);
            rs += __shfl_xor(rs, 32);
            l_r = l_r * aa + rs;
            float al_[4];
            #pragma unroll
            for (int r = 0; r < 4; ++r) al_[r] = __shfl(aa, quad * 4 + r);
            #pragma unroll
            for (int nd = 0; nd < 4; ++nd)
                #pragma unroll
                for (int r = 0; r < 4; ++r)
                    O[nd][r] *= al_[r];
            bf16x8 pf[2];
            #pragma unroll
            for (int kk = 0; kk < 2; ++kk)
                pf[kk] = *(const bf16x8*)&myP[lr * 68 + kk * 32 + quad * 8];
            #pragma unroll
            for (int nd = 0; nd < 4; ++nd)
                #pragma unroll
                for (int kk = 0; kk < 2; ++kk)
                    O[nd] = MFMA16(pf[kk], vf[nd][kk], O[nd]);
        }
    }
    if (quad == 0)
        mlpart[(size_t)z * RR + (size_t)bh * SS + row0 + lr] =
            make_float2(cscale * m_r, l_r);
    #pragma unroll
    for (int r = 0; r < 4; ++r) {
        size_t rowg = (size_t)bh * SS + row0 + quad * 4 + r;
        #pragma unroll
        for (int nd = 0; nd < 4; ++nd)
            Opart[((size_t)z * RR + rowg) * DD + nd * 16 + lr] =
                __float2half(O[nd][r]);
    }
}

// merge K-split halves; write ctx bf16 (hi only — O-proj is plain bf16)
__global__ __launch_bounds__(256) void combine_attn(
        const __half* __restrict__ Opart, const float2* __restrict__ mlpart,
        unsigned short* __restrict__ ctxhi) {
    int tid = blockIdx.x * 256 + threadIdx.x;
    int row = tid >> 4, c4 = (tid & 15) * 4;
    float2 ml0 = mlpart[row];
    float2 ml1 = mlpart[RR + row];
    float ms = fmaxf(ml0.x, ml1.x);
    float a0 = EXP2(ml0.x - ms), a1 = EXP2(ml1.x - ms);
    float inv = RCPF(ml0.y * a0 + ml1.y * a1);
    a0 *= inv; a1 *= inv;
    const __half* p0 = Opart + (size_t)row * DD + c4;
    const __half* p1 = p0 + (size_t)RR * DD;
    int bh = row >> 11, s = row & (SS - 1);
    int b = bh >> 4, h = bh & 15;
    size_t idx = ((size_t)b * SS + s) * EE + h * DD + c4;
    ushort4 hv;
    unsigned short* hp = (unsigned short*)&hv;
    #pragma unroll
    for (int j = 0; j < 4; ++j) {
        float o = __half2float(p0[j]) * a0 + __half2float(p1[j]) * a1;
        hp[j] = f2bf(o);
    }
    *(ushort4*)&ctxhi[idx] = hv;
}

extern "C" void kernel_launch(void* const* d_in, const int* in_sizes, int n_in,
                              void* d_out, int out_size, void* d_ws, size_t ws_size,
                              hipStream_t stream) {
    const float* x     = (const float*)d_in[0];
    const float* Wq    = (const float*)d_in[1];
    const float* bq    = (const float*)d_in[2];
    const float* Wk    = (const float*)d_in[3];
    const float* bk    = (const float*)d_in[4];
    const float* Wv    = (const float*)d_in[5];
    const float* bv    = (const float*)d_in[6];
    const float* Wo    = (const float*)d_in[7];
    const float* bo    = (const float*)d_in[8];
    const float* alpha = (const float*)d_in[9];
    float* out = (float*)d_out;
    char* ws = (char*)d_ws;

    const int M = BB * SS;                 // 4096
    const size_t MB = 1u << 20;
    unsigned short* xhi  = (unsigned short*)(ws + 0 * MB);   // later: ctxhi
    unsigned short* xlo  = (unsigned short*)(ws + 8 * MB);
    unsigned short* Whi  = (unsigned short*)(ws + 16 * MB);  // 6 MB (qkv concat)
    unsigned short* Wlo  = (unsigned short*)(ws + 22 * MB);  // 4 MB used (q,k)
    unsigned short* vt   = (unsigned short*)(ws + 16 * MB);  // reuses dead W area
    float2* mlpart       = (float2*)(ws + 24 * MB);          // 1 MB
    unsigned short* Wohi = (unsigned short*)(ws + 28 * MB);
    unsigned short* qhi  = (unsigned short*)(ws + 32 * MB);
    unsigned short* qlo  = (unsigned short*)(ws + 40 * MB);
    unsigned short* khi  = (unsigned short*)(ws + 48 * MB);
    unsigned short* v_sd = (unsigned short*)(ws + 64 * MB);  // dead after transpose
    __half* Opart        = (__half*)(ws + 64 * MB);          // 16 MB (reuses v_sd)
    float* sqn = (float*)(ws + 80 * MB);
    float* skn = (float*)(ws + 80 * MB + 256 * 1024);
    unsigned short* ctxhi = xhi;

    const int nX = M * EE / 4, nW = EE * EE / 4;
    split_f32<<<nX / 256, 256, 0, stream>>>(x, xhi, xlo, nX);
    split_w4<<<dim3(nW / 256, 4), 256, 0, stream>>>(Wq, Wk, Wv, Wo, Whi, Wlo, Wohi);

    // Q/K projections: 3-pass (K=1024 — 2-pass would inject ~0.03 into q/k)
    gemm3p<1, 3><<<dim3(2 * EE / 128, M / 128), 256, 0, stream>>>(
        xhi, xlo, Whi, Wlo, bq, bk, nullptr, nullptr,
        qhi, qlo, khi, nullptr, sqn, skn, M, 2 * EE, EE);
    // V projection: plain bf16 (consumed as bf16 anyway)
    gemm3p<2, 1><<<dim3(EE / 128, M / 128), 256, 0, stream>>>(
        xhi, nullptr, Whi + 2 * (size_t)EE * EE, nullptr, nullptr, nullptr, bv, nullptr,
        nullptr, nullptr, nullptr, v_sd, nullptr, nullptr, M, EE, EE);

    transpose_v<<<dim3(SS / 64, BB * HH), 256, 0, stream>>>(v_sd, vt);

    yat_attn_mfma<<<dim3(SS / 64, BB * HH, 2), 256, 0, stream>>>(
        qhi, qlo, khi, vt, sqn, skn, alpha, Opart, mlpart);

    combine_attn<<<RR * 16 / 256, 256, 0, stream>>>(Opart, mlpart, ctxhi);

    // O projection: plain bf16 (error ~6e-4 ≪ threshold)
    gemm3p<0, 1><<<dim3(EE / 128, M / 128), 256, 0, stream>>>(
        ctxhi, nullptr, Wohi, nullptr, bo, nullptr, nullptr, out,
        nullptr, nullptr, nullptr, nullptr, nullptr, nullptr, M, EE, EE);
}